// Round 1
// baseline (1848.328 us; speedup 1.0000x reference)
//
#include <hip/hip_runtime.h>
#include <hip/hip_bf16.h>
#include <math.h>

#define N_Gc 50000
#define N_Dc 50000
#define DIM 64
#define RNK 32
#define NNZc 1600000
#define BSZ 2048
#define KEEPV (1.0f/0.9f)
#define INVT 5.0f
#define LPAD 68
#define JSEG 49

// ---------------- CSR/CSC build ----------------
__global__ void hist_kernel(const int* __restrict__ rows, const int* __restrict__ cols,
                            int* __restrict__ cur_r, int* __restrict__ cur_c) {
  int e = blockIdx.x*256 + threadIdx.x;
  if (e < NNZc) {
    atomicAdd(&cur_r[rows[e]], 1);
    atomicAdd(&cur_c[cols[e]], 1);
  }
}

__global__ __launch_bounds__(1024) void scan2_kernel(int* curA, int* ptrA, int* curB, int* ptrB, int n) {
  int* cur = blockIdx.x ? curB : curA;
  int* ptr = blockIdx.x ? ptrB : ptrA;
  __shared__ int wsum[16];
  int t = threadIdx.x, lane = t & 63, w = t >> 6;
  int carry = 0;
  for (int base = 0; base < n; base += 1024) {
    int i = base + t;
    int v = (i < n) ? cur[i] : 0;
    int x = v;
    #pragma unroll
    for (int o = 1; o < 64; o <<= 1) { int y = __shfl_up(x, o); if (lane >= o) x += y; }
    if (lane == 63) wsum[w] = x;
    __syncthreads();
    if (t < 16) {
      int s = wsum[t];
      #pragma unroll
      for (int o = 1; o < 16; o <<= 1) { int y = __shfl_up(s, o); if (t >= o) s += y; }
      wsum[t] = s;
    }
    __syncthreads();
    int wpre = (w == 0) ? 0 : wsum[w-1];
    int total = wsum[15];
    int ex = carry + wpre + (x - v);
    if (i < n) { ptr[i] = ex; cur[i] = ex; }
    carry += total;
    __syncthreads();
  }
  if (t == 0) ptr[n] = carry;
}

__global__ void scatter_kernel(const int* __restrict__ rows, const int* __restrict__ cols,
                               int* cur_r, int* cur_c,
                               int* __restrict__ perm_r, int* __restrict__ perm_c) {
  int e = blockIdx.x*256 + threadIdx.x;
  if (e < NNZc) {
    int p = atomicAdd(&cur_r[rows[e]], 1); perm_r[p] = e;
    int q = atomicAdd(&cur_c[cols[e]], 1); perm_c[q] = e;
  }
}

// ---------------- SpMM: wave per row, lane = dim ----------------
__global__ __launch_bounds__(256) void spmm_kernel(const int* __restrict__ ptr, const int* __restrict__ perm,
    const int* __restrict__ oidx, const float* __restrict__ vals, const float* __restrict__ drop,
    const float* __restrict__ Esrc, float* __restrict__ Zdst, int nrows) {
  int lane = threadIdx.x & 63;
  int row = blockIdx.x*4 + (threadIdx.x >> 6);
  if (row >= nrows) return;
  int k = ptr[row], end = ptr[row+1];
  float acc = 0.f;
  for (; k + 4 <= end; k += 4) {
    int e0 = perm[k], e1 = perm[k+1], e2 = perm[k+2], e3 = perm[k+3];
    int c0 = oidx[e0], c1 = oidx[e1], c2 = oidx[e2], c3 = oidx[e3];
    float w0 = vals[e0]*((drop[e0] > 0.1f) ? KEEPV : 0.f);
    float w1 = vals[e1]*((drop[e1] > 0.1f) ? KEEPV : 0.f);
    float w2 = vals[e2]*((drop[e2] > 0.1f) ? KEEPV : 0.f);
    float w3 = vals[e3]*((drop[e3] > 0.1f) ? KEEPV : 0.f);
    float g0 = Esrc[(size_t)c0*DIM + lane];
    float g1 = Esrc[(size_t)c1*DIM + lane];
    float g2 = Esrc[(size_t)c2*DIM + lane];
    float g3 = Esrc[(size_t)c3*DIM + lane];
    acc += w0*g0; acc += w1*g1; acc += w2*g2; acc += w3*g3;
  }
  for (; k < end; k++) {
    int e0 = perm[k]; int c0 = oidx[e0];
    float w0 = vals[e0]*((drop[e0] > 0.1f) ? KEEPV : 0.f);
    acc += w0*Esrc[(size_t)c0*DIM + lane];
  }
  Zdst[(size_t)row*DIM + lane] = acc;
}

// ---------------- Egs = a + b + c (float4) ----------------
__global__ __launch_bounds__(256) void add3_kernel(const float4* __restrict__ a, const float4* __restrict__ b,
    const float4* __restrict__ c, float4* __restrict__ o, int n4) {
  int i = blockIdx.x*256 + threadIdx.x;
  if (i < n4) {
    float4 va = a[i], vb = b[i], vc = c[i];
    float4 r;
    r.x = va.x + vb.x + vc.x; r.y = va.y + vb.y + vc.y;
    r.z = va.z + vb.z + vc.z; r.w = va.w + vb.w + vc.w;
    o[i] = r;
  }
}

// ---------------- M[32][64] = vrow @ (E0 + Z0) ----------------
__global__ __launch_bounds__(256) void matred_kernel(const float* __restrict__ vrow,
    const float* __restrict__ E0, const float* __restrict__ Z0, float* __restrict__ M, int n) {
  __shared__ float part[RNK*DIM];
  int t = threadIdx.x, lane = t & 63, w = t >> 6;
  for (int i = t; i < RNK*DIM; i += 256) part[i] = 0.f;
  __syncthreads();
  int nw = gridDim.x*4;
  int wid = blockIdx.x*4 + w;
  int chunk = (n + nw - 1)/nw;
  int i0 = wid*chunk, i1 = min(n, i0 + chunk);
  float acc[RNK];
  #pragma unroll
  for (int r = 0; r < RNK; r++) acc[r] = 0.f;
  for (int i = i0; i < i1; i++) {
    float x = E0[(size_t)i*DIM + lane] + Z0[(size_t)i*DIM + lane];
    #pragma unroll
    for (int r = 0; r < RNK; r++) acc[r] += vrow[(size_t)r*n + i]*x;
  }
  #pragma unroll
  for (int r = 0; r < RNK; r++) atomicAdd(&part[r*DIM + lane], acc[r]);
  __syncthreads();
  for (int i = t; i < RNK*DIM; i += 256) atomicAdd(&M[i], part[i]);
}

// ---------------- G rows at sampled ids: out[b] = E0[id] + mul[id] @ M ----------------
__global__ __launch_bounds__(256) void gsmall_kernel(const int* __restrict__ ids,
    const float* __restrict__ E0, const float* __restrict__ mul, const float* __restrict__ M,
    float* __restrict__ out) {
  __shared__ float Ms[RNK*DIM];
  int t = threadIdx.x;
  for (int i = t; i < RNK*DIM; i += 256) Ms[i] = M[i];
  __syncthreads();
  int b = blockIdx.x*4 + (t >> 6), lane = t & 63;
  int u = ids[b];
  float a = E0[(size_t)u*DIM + lane];
  #pragma unroll
  for (int r = 0; r < RNK; r++) a += mul[(size_t)u*RNK + r]*Ms[r*DIM + lane];
  out[(size_t)b*DIM + lane] = a;
}

// ---------------- fused GEMM + exp + row-sum: sumexp[b] += sum_j exp(A[b].X[j]*INVT) ----------------
__global__ __launch_bounds__(256) void lse_kernel(const float* __restrict__ A,
    const float* __restrict__ X, int nj, float* __restrict__ sumexp) {
  __shared__ float As[DIM*LPAD];
  __shared__ float Xs[DIM*LPAD];
  __shared__ float accs[64];
  int t = threadIdx.x;
  int bt = blockIdx.x & 31, js = blockIdx.x >> 5;
  int b0 = bt*64;
  if (t < 64) accs[t] = 0.f;
  // stage A^T once (64 rows x 64 k), padded stride
  {
    int r = t >> 2, koff = (t & 3)*16;
    #pragma unroll
    for (int ii = 0; ii < 4; ii++) {
      float4 v = *(const float4*)&A[(size_t)(b0 + r)*DIM + koff + ii*4];
      As[(koff+ii*4+0)*LPAD + r] = v.x;
      As[(koff+ii*4+1)*LPAD + r] = v.y;
      As[(koff+ii*4+2)*LPAD + r] = v.z;
      As[(koff+ii*4+3)*LPAD + r] = v.w;
    }
  }
  int bq = t & 15, jq = t >> 4;
  float sum[4] = {0.f, 0.f, 0.f, 0.f};
  int njt = (nj + 63) >> 6;
  for (int jt = js; jt < njt; jt += JSEG) {
    int j0 = jt << 6;
    __syncthreads();  // previous tile's compute done before restaging Xs
    {
      int r = t >> 2, koff = (t & 3)*16;
      int j = j0 + r;
      #pragma unroll
      for (int ii = 0; ii < 4; ii++) {
        float4 v = (j < nj) ? *(const float4*)&X[(size_t)j*DIM + koff + ii*4]
                            : make_float4(0.f,0.f,0.f,0.f);
        Xs[(koff+ii*4+0)*LPAD + r] = v.x;
        Xs[(koff+ii*4+1)*LPAD + r] = v.y;
        Xs[(koff+ii*4+2)*LPAD + r] = v.z;
        Xs[(koff+ii*4+3)*LPAD + r] = v.w;
      }
    }
    __syncthreads();
    float acc[16];
    #pragma unroll
    for (int i = 0; i < 16; i++) acc[i] = 0.f;
    #pragma unroll 8
    for (int k = 0; k < 64; k++) {
      float4 a4 = *(const float4*)&As[k*LPAD + bq*4];
      float4 x4 = *(const float4*)&Xs[k*LPAD + jq*4];
      float av[4] = {a4.x, a4.y, a4.z, a4.w};
      float xv[4] = {x4.x, x4.y, x4.z, x4.w};
      #pragma unroll
      for (int i = 0; i < 4; i++)
        #pragma unroll
        for (int q = 0; q < 4; q++)
          acc[i*4+q] += av[i]*xv[q];
    }
    int jb = j0 + jq*4;
    #pragma unroll
    for (int i = 0; i < 4; i++) {
      #pragma unroll
      for (int q = 0; q < 4; q++) {
        float e = __expf(acc[i*4+q]*INVT);
        if (jb + q < nj) sum[i] += e;
      }
    }
  }
  #pragma unroll
  for (int i = 0; i < 4; i++) atomicAdd(&accs[bq*4 + i], sum[i]);
  __syncthreads();
  if (t < 64) atomicAdd(&sumexp[b0 + t], accs[t]);
}

// ---------------- sum of squares (reg term) ----------------
__global__ __launch_bounds__(256) void sumsq_kernel(const float* __restrict__ x, int n4, float* __restrict__ acc) {
  int idx = blockIdx.x*256 + threadIdx.x;
  int stride = gridDim.x*256;
  float s = 0.f;
  for (int i = idx; i < n4; i += stride) {
    float4 v = ((const float4*)x)[i];
    s += v.x*v.x + v.y*v.y + v.z*v.z + v.w*v.w;
  }
  #pragma unroll
  for (int o = 32; o > 0; o >>= 1) s += __shfl_xor(s, o);
  if ((threadIdx.x & 63) == 0) atomicAdd(acc, s);
}

// ---------------- per-sample terms: pos-score, BPR, neg logs ----------------
__global__ __launch_bounds__(256) void perb_kernel(const int* __restrict__ uids, const int* __restrict__ iids,
    const int* __restrict__ pos, const int* __restrict__ neg,
    const float* __restrict__ Ggu, const float* __restrict__ Gdi,
    const float* __restrict__ Egs, const float* __restrict__ Eds,
    const float* __restrict__ seg, const float* __restrict__ sed,
    float* __restrict__ accs) {
  int t = threadIdx.x, lane = t & 63;
  int b = blockIdx.x*4 + (t >> 6);
  int u = uids[b], it = iids[b], p = pos[b], ng = neg[b];
  float egu = Egs[(size_t)u*DIM + lane];
  float d1 = Ggu[(size_t)b*DIM + lane]*egu;
  float d2 = Gdi[(size_t)b*DIM + lane]*Eds[(size_t)it*DIM + lane];
  float d3 = egu*Eds[(size_t)p*DIM + lane];
  float d4 = egu*Eds[(size_t)ng*DIM + lane];
  #pragma unroll
  for (int o = 32; o > 0; o >>= 1) {
    d1 += __shfl_xor(d1, o);
    d2 += __shfl_xor(d2, o);
    d3 += __shfl_xor(d3, o);
    d4 += __shfl_xor(d4, o);
  }
  if (lane == 0) {
    float pterm = fminf(fmaxf(d1*INVT, -5.f), 5.f) + fminf(fmaxf(d2*INVT, -5.f), 5.f);
    float diff = d3 - d4;
    float lr = log1pf(expf(-diff));  // -log(sigmoid(diff))
    float lg = logf(seg[b] + 1e-8f) + logf(sed[b] + 1e-8f);
    atomicAdd(&accs[0], pterm);
    atomicAdd(&accs[1], lr);
    atomicAdd(&accs[2], lg);
  }
}

__global__ void final_kernel(const float* __restrict__ accs, float* __restrict__ out) {
  float posm = accs[0]*(1.f/BSZ);
  float lr   = accs[1]*(1.f/BSZ);
  float negm = accs[2]*(1.f/BSZ);
  float reg  = 1e-7f*accs[3];
  float l1ls = 0.2f*(negm - posm);
  out[0] = lr + l1ls + reg;
  out[1] = lr;
  out[2] = l1ls;
}

extern "C" void kernel_launch(void* const* d_in, const int* in_sizes, int n_in,
                              void* d_out, int out_size, void* d_ws, size_t ws_size,
                              hipStream_t stream) {
  (void)in_sizes; (void)n_in; (void)out_size;
  const int*   uids = (const int*)d_in[0];
  const int*   iids = (const int*)d_in[1];
  const int*   pos  = (const int*)d_in[2];
  const int*   neg  = (const int*)d_in[3];
  const float* Eg0  = (const float*)d_in[4];
  const float* Ed0  = (const float*)d_in[5];
  const int*   rows = (const int*)d_in[6];
  const int*   cols = (const int*)d_in[7];
  const float* vals = (const float*)d_in[8];
  const float* gms  = (const float*)d_in[9];
  const float* vms  = (const float*)d_in[10];
  const float* ut   = (const float*)d_in[11];
  const float* vt   = (const float*)d_in[12];
  const float* drop = (const float*)d_in[13];
  float* out = (float*)d_out;

  float* ws = (float*)d_ws;
  const size_t ED = (size_t)N_Gc*DIM;  // 3.2M floats
  float* Zg0 = ws;
  float* Zd0 = Zg0 + ED;
  float* Zg1 = Zd0 + ED;
  float* Zd1 = Zg1 + ED;
  float* Egs = Zd1 + ED;
  float* Eds = Egs + ED;
  int* ptr_r = (int*)(Eds + ED);
  int* ptr_c = ptr_r + (N_Gc + 1);
  int* cur_r = ptr_c + (N_Dc + 1);
  int* cur_c = cur_r + (N_Gc + 1);
  int* perm_r = cur_c + (N_Dc + 1);
  int* perm_c = perm_r + NNZc;
  float* Ggu = (float*)(perm_c + NNZc);
  float* Gdi = Ggu + (size_t)BSZ*DIM;
  float* Mg  = Gdi + (size_t)BSZ*DIM;   // zeroed zone starts here
  float* Md  = Mg + RNK*DIM;
  float* seg = Md + RNK*DIM;
  float* sed = seg + BSZ;
  float* accs = sed + BSZ;              // 16 floats

  size_t need = ((char*)(accs + 16)) - ((char*)d_ws);
  if (ws_size < need) return;  // workspace too small: fail loudly (validation will catch)

  hipMemsetAsync(cur_r, 0, sizeof(int)*((N_Gc+1) + (N_Dc+1)), stream);
  hipMemsetAsync(Mg, 0, sizeof(float)*(2*RNK*DIM + 2*BSZ + 16), stream);

  hist_kernel<<<(NNZc + 255)/256, 256, 0, stream>>>(rows, cols, cur_r, cur_c);
  scan2_kernel<<<2, 1024, 0, stream>>>(cur_r, ptr_r, cur_c, ptr_c, N_Gc);
  scatter_kernel<<<(NNZc + 255)/256, 256, 0, stream>>>(rows, cols, cur_r, cur_c, perm_r, perm_c);

  int spmm_blocks = (N_Gc + 3)/4;
  // layer 0 (inputs E_g_0 / E_d_0)
  spmm_kernel<<<spmm_blocks, 256, 0, stream>>>(ptr_r, perm_r, cols, vals, drop + 0*(size_t)NNZc, Ed0, Zg0, N_Gc);
  spmm_kernel<<<spmm_blocks, 256, 0, stream>>>(ptr_c, perm_c, rows, vals, drop + 1*(size_t)NNZc, Eg0, Zd0, N_Dc);
  // layer 1 (inputs Z_d0 / Z_g0)
  spmm_kernel<<<spmm_blocks, 256, 0, stream>>>(ptr_r, perm_r, cols, vals, drop + 2*(size_t)NNZc, Zd0, Zg1, N_Gc);
  spmm_kernel<<<spmm_blocks, 256, 0, stream>>>(ptr_c, perm_c, rows, vals, drop + 3*(size_t)NNZc, Zg0, Zd1, N_Dc);

  int n4 = (int)(ED/4);
  add3_kernel<<<(n4 + 255)/256, 256, 0, stream>>>((const float4*)Eg0, (const float4*)Zg0, (const float4*)Zg1, (float4*)Egs, n4);
  add3_kernel<<<(n4 + 255)/256, 256, 0, stream>>>((const float4*)Ed0, (const float4*)Zd0, (const float4*)Zd1, (float4*)Eds, n4);

  // Mg = vt @ (Ed0 + Zd0) ; Md = ut @ (Eg0 + Zg0)
  matred_kernel<<<64, 256, 0, stream>>>(vt, Ed0, Zd0, Mg, N_Dc);
  matred_kernel<<<64, 256, 0, stream>>>(ut, Eg0, Zg0, Md, N_Gc);

  // G_g_sum rows at uids ; G_d_sum rows at iids
  gsmall_kernel<<<BSZ/4, 256, 0, stream>>>(uids, Eg0, gms, Mg, Ggu);
  gsmall_kernel<<<BSZ/4, 256, 0, stream>>>(iids, Ed0, vms, Md, Gdi);

  lse_kernel<<<32*JSEG, 256, 0, stream>>>(Ggu, Egs, N_Gc, seg);
  lse_kernel<<<32*JSEG, 256, 0, stream>>>(Gdi, Eds, N_Dc, sed);

  sumsq_kernel<<<1024, 256, 0, stream>>>(Eg0, n4, accs + 3);
  sumsq_kernel<<<1024, 256, 0, stream>>>(Ed0, n4, accs + 3);

  perb_kernel<<<BSZ/4, 256, 0, stream>>>(uids, iids, pos, neg, Ggu, Gdi, Egs, Eds, seg, sed, accs);
  final_kernel<<<1, 1, 0, stream>>>(accs, out);
}

// Round 2
// 1731.465 us; speedup vs baseline: 1.0675x; 1.0675x over previous
//
#include <hip/hip_runtime.h>
#include <hip/hip_bf16.h>
#include <math.h>

#define N_Gc 50000
#define N_Dc 50000
#define DIM 64
#define RNK 32
#define NNZc 1600000
#define BSZ 2048
#define KEEPV (1.0f/0.9f)
#define INVT 5.0f
#define LPAD 68
#define JSEG 49
#define NBK 782   // (50000+63)/64 buckets of 64 rows

// ---------------- per-row/col histogram ----------------
__global__ void hist_kernel(const int* __restrict__ rows, const int* __restrict__ cols,
                            int* __restrict__ cur_r, int* __restrict__ cur_c) {
  int e = blockIdx.x*256 + threadIdx.x;
  if (e < NNZc) {
    atomicAdd(&cur_r[rows[e]], 1);
    atomicAdd(&cur_c[cols[e]], 1);
  }
}

__global__ __launch_bounds__(1024) void scan2_kernel(int* curA, int* ptrA, int* curB, int* ptrB, int n) {
  int* cur = blockIdx.x ? curB : curA;
  int* ptr = blockIdx.x ? ptrB : ptrA;
  __shared__ int wsum[16];
  int t = threadIdx.x, lane = t & 63, w = t >> 6;
  int carry = 0;
  for (int base = 0; base < n; base += 1024) {
    int i = base + t;
    int v = (i < n) ? cur[i] : 0;
    int x = v;
    #pragma unroll
    for (int o = 1; o < 64; o <<= 1) { int y = __shfl_up(x, o); if (lane >= o) x += y; }
    if (lane == 63) wsum[w] = x;
    __syncthreads();
    if (t < 16) {
      int s = wsum[t];
      #pragma unroll
      for (int o = 1; o < 16; o <<= 1) { int y = __shfl_up(s, o); if (t >= o) s += y; }
      wsum[t] = s;
    }
    __syncthreads();
    int wpre = (w == 0) ? 0 : wsum[w-1];
    int total = wsum[15];
    int ex = carry + wpre + (x - v);
    if (i < n) ptr[i] = ex;
    carry += total;
    __syncthreads();
  }
  if (t == 0) ptr[n] = carry;
}

// bucket cursors start at ptr[first row of bucket]
__global__ void initb_kernel(const int* __restrict__ ptr_r, const int* __restrict__ ptr_c,
                             int* __restrict__ bcur_r, int* __restrict__ bcur_c) {
  int b = blockIdx.x*256 + threadIdx.x;
  if (b <= NBK) {
    int r = min(b*64, N_Gc);
    bcur_r[b] = ptr_r[r];
    bcur_c[b] = ptr_c[r];
  }
}

// ---------------- phase A: scatter packed records into bucket regions ----------------
__global__ __launch_bounds__(256) void phaseA_kernel(const int* __restrict__ rows, const int* __restrict__ cols,
    const float* __restrict__ vals, const float* __restrict__ drop,
    int* __restrict__ bcur_r, int* __restrict__ bcur_c,
    int4* __restrict__ stage_r, int4* __restrict__ stage_c) {
  int e = blockIdx.x*256 + threadIdx.x;
  if (e >= NNZc) return;
  int r = rows[e], c = cols[e];
  float v = vals[e];
  float wr0 = v*((drop[e] > 0.1f) ? KEEPV : 0.f);                    // layer0, A side
  float wc0 = v*((drop[(size_t)NNZc + e] > 0.1f) ? KEEPV : 0.f);    // layer0, A^T side
  float wr1 = v*((drop[2*(size_t)NNZc + e] > 0.1f) ? KEEPV : 0.f);  // layer1, A side
  float wc1 = v*((drop[3*(size_t)NNZc + e] > 0.1f) ? KEEPV : 0.f);  // layer1, A^T side
  int p = atomicAdd(&bcur_r[r >> 6], 1);
  stage_r[p] = make_int4(c, __float_as_int(wr0), __float_as_int(wr1), r);
  int q = atomicAdd(&bcur_c[c >> 6], 1);
  stage_c[q] = make_int4(r, __float_as_int(wc0), __float_as_int(wc1), c);
}

// ---------------- phase B: within-bucket counting sort to exact CSR slots ----------------
__global__ __launch_bounds__(256) void phaseB_kernel(const int* __restrict__ ptr,
    const int4* __restrict__ stage, int* __restrict__ fcol,
    float* __restrict__ fw0, float* __restrict__ fw1, int n) {
  __shared__ int cnt[64];
  int t = threadIdx.x;
  int base_row = blockIdx.x*64;
  int lastrow = min(base_row + 64, n);
  int base = ptr[base_row];
  int endp = ptr[lastrow];
  if (t < 64) {
    int rr = base_row + t;
    cnt[t] = (rr < n) ? (ptr[rr] - base) : 0;
  }
  __syncthreads();
  for (int k = base + t; k < endp; k += 256) {
    int4 rec = stage[k];
    int rel = rec.w - base_row;
    int pos = base + atomicAdd(&cnt[rel], 1);
    fcol[pos] = rec.x;
    fw0[pos] = __int_as_float(rec.y);
    fw1[pos] = __int_as_float(rec.z);
  }
}

// ---------------- SpMM: wave per row, lane = dim, sequential records ----------------
__global__ __launch_bounds__(256) void spmm2_kernel(const int* __restrict__ ptr,
    const int* __restrict__ fcol, const float* __restrict__ fw,
    const float* __restrict__ Esrc, float* __restrict__ Zdst,
    const float* __restrict__ addA, const float* __restrict__ addB, int nrows) {
  int lane = threadIdx.x & 63;
  int row = blockIdx.x*4 + (threadIdx.x >> 6);
  if (row >= nrows) return;
  int k = ptr[row], end = ptr[row+1];
  float acc = 0.f;
  for (; k + 4 <= end; k += 4) {
    int c0 = fcol[k], c1 = fcol[k+1], c2 = fcol[k+2], c3 = fcol[k+3];
    float w0 = fw[k], w1 = fw[k+1], w2 = fw[k+2], w3 = fw[k+3];
    float g0 = Esrc[(size_t)c0*DIM + lane];
    float g1 = Esrc[(size_t)c1*DIM + lane];
    float g2 = Esrc[(size_t)c2*DIM + lane];
    float g3 = Esrc[(size_t)c3*DIM + lane];
    acc += w0*g0; acc += w1*g1; acc += w2*g2; acc += w3*g3;
  }
  for (; k < end; k++)
    acc += fw[k]*Esrc[(size_t)fcol[k]*DIM + lane];
  size_t o = (size_t)row*DIM + lane;
  if (addA != nullptr) acc += addA[o] + addB[o];   // fused E_sum = E0 + Z0 + Z1
  Zdst[o] = acc;
}

// ---------------- M[32][64] = vrow @ (E0 + Z0) ----------------
__global__ __launch_bounds__(256) void matred_kernel(const float* __restrict__ vrow,
    const float* __restrict__ E0, const float* __restrict__ Z0, float* __restrict__ M, int n) {
  __shared__ float part[RNK*DIM];
  int t = threadIdx.x, lane = t & 63, w = t >> 6;
  for (int i = t; i < RNK*DIM; i += 256) part[i] = 0.f;
  __syncthreads();
  int nw = gridDim.x*4;
  int wid = blockIdx.x*4 + w;
  int chunk = (n + nw - 1)/nw;
  int i0 = wid*chunk, i1 = min(n, i0 + chunk);
  float acc[RNK];
  #pragma unroll
  for (int r = 0; r < RNK; r++) acc[r] = 0.f;
  for (int i = i0; i < i1; i++) {
    float x = E0[(size_t)i*DIM + lane] + Z0[(size_t)i*DIM + lane];
    #pragma unroll
    for (int r = 0; r < RNK; r++) acc[r] += vrow[(size_t)r*n + i]*x;
  }
  #pragma unroll
  for (int r = 0; r < RNK; r++) atomicAdd(&part[r*DIM + lane], acc[r]);
  __syncthreads();
  for (int i = t; i < RNK*DIM; i += 256) atomicAdd(&M[i], part[i]);
}

// ---------------- G rows at sampled ids ----------------
__global__ __launch_bounds__(256) void gsmall_kernel(const int* __restrict__ ids,
    const float* __restrict__ E0, const float* __restrict__ mul, const float* __restrict__ M,
    float* __restrict__ out) {
  __shared__ float Ms[RNK*DIM];
  int t = threadIdx.x;
  for (int i = t; i < RNK*DIM; i += 256) Ms[i] = M[i];
  __syncthreads();
  int b = blockIdx.x*4 + (t >> 6), lane = t & 63;
  int u = ids[b];
  float a = E0[(size_t)u*DIM + lane];
  #pragma unroll
  for (int r = 0; r < RNK; r++) a += mul[(size_t)u*RNK + r]*Ms[r*DIM + lane];
  out[(size_t)b*DIM + lane] = a;
}

// ---------------- fused GEMM + exp + row-sum ----------------
__global__ __launch_bounds__(256) void lse_kernel(const float* __restrict__ A,
    const float* __restrict__ X, int nj, float* __restrict__ sumexp) {
  __shared__ float As[DIM*LPAD];
  __shared__ float Xs[DIM*LPAD];
  __shared__ float accs[64];
  int t = threadIdx.x;
  int bt = blockIdx.x & 31, js = blockIdx.x >> 5;
  int b0 = bt*64;
  if (t < 64) accs[t] = 0.f;
  {
    int r = t >> 2, koff = (t & 3)*16;
    #pragma unroll
    for (int ii = 0; ii < 4; ii++) {
      float4 v = *(const float4*)&A[(size_t)(b0 + r)*DIM + koff + ii*4];
      As[(koff+ii*4+0)*LPAD + r] = v.x;
      As[(koff+ii*4+1)*LPAD + r] = v.y;
      As[(koff+ii*4+2)*LPAD + r] = v.z;
      As[(koff+ii*4+3)*LPAD + r] = v.w;
    }
  }
  int bq = t & 15, jq = t >> 4;
  float sum[4] = {0.f, 0.f, 0.f, 0.f};
  int njt = (nj + 63) >> 6;
  for (int jt = js; jt < njt; jt += JSEG) {
    int j0 = jt << 6;
    __syncthreads();
    {
      int r = t >> 2, koff = (t & 3)*16;
      int j = j0 + r;
      #pragma unroll
      for (int ii = 0; ii < 4; ii++) {
        float4 v = (j < nj) ? *(const float4*)&X[(size_t)j*DIM + koff + ii*4]
                            : make_float4(0.f,0.f,0.f,0.f);
        Xs[(koff+ii*4+0)*LPAD + r] = v.x;
        Xs[(koff+ii*4+1)*LPAD + r] = v.y;
        Xs[(koff+ii*4+2)*LPAD + r] = v.z;
        Xs[(koff+ii*4+3)*LPAD + r] = v.w;
      }
    }
    __syncthreads();
    float acc[16];
    #pragma unroll
    for (int i = 0; i < 16; i++) acc[i] = 0.f;
    #pragma unroll 8
    for (int k = 0; k < 64; k++) {
      float4 a4 = *(const float4*)&As[k*LPAD + bq*4];
      float4 x4 = *(const float4*)&Xs[k*LPAD + jq*4];
      float av[4] = {a4.x, a4.y, a4.z, a4.w};
      float xv[4] = {x4.x, x4.y, x4.z, x4.w};
      #pragma unroll
      for (int i = 0; i < 4; i++)
        #pragma unroll
        for (int q = 0; q < 4; q++)
          acc[i*4+q] += av[i]*xv[q];
    }
    int jb = j0 + jq*4;
    #pragma unroll
    for (int i = 0; i < 4; i++) {
      #pragma unroll
      for (int q = 0; q < 4; q++) {
        float e = __expf(acc[i*4+q]*INVT);
        if (jb + q < nj) sum[i] += e;
      }
    }
  }
  #pragma unroll
  for (int i = 0; i < 4; i++) atomicAdd(&accs[bq*4 + i], sum[i]);
  __syncthreads();
  if (t < 64) atomicAdd(&sumexp[b0 + t], accs[t]);
}

// ---------------- sum of squares ----------------
__global__ __launch_bounds__(256) void sumsq_kernel(const float* __restrict__ x, int n4, float* __restrict__ acc) {
  int idx = blockIdx.x*256 + threadIdx.x;
  int stride = gridDim.x*256;
  float s = 0.f;
  for (int i = idx; i < n4; i += stride) {
    float4 v = ((const float4*)x)[i];
    s += v.x*v.x + v.y*v.y + v.z*v.z + v.w*v.w;
  }
  #pragma unroll
  for (int o = 32; o > 0; o >>= 1) s += __shfl_xor(s, o);
  if ((threadIdx.x & 63) == 0) atomicAdd(acc, s);
}

// ---------------- per-sample terms ----------------
__global__ __launch_bounds__(256) void perb_kernel(const int* __restrict__ uids, const int* __restrict__ iids,
    const int* __restrict__ pos, const int* __restrict__ neg,
    const float* __restrict__ Ggu, const float* __restrict__ Gdi,
    const float* __restrict__ Egs, const float* __restrict__ Eds,
    const float* __restrict__ seg, const float* __restrict__ sed,
    float* __restrict__ accs) {
  int t = threadIdx.x, lane = t & 63;
  int b = blockIdx.x*4 + (t >> 6);
  int u = uids[b], it = iids[b], p = pos[b], ng = neg[b];
  float egu = Egs[(size_t)u*DIM + lane];
  float d1 = Ggu[(size_t)b*DIM + lane]*egu;
  float d2 = Gdi[(size_t)b*DIM + lane]*Eds[(size_t)it*DIM + lane];
  float d3 = egu*Eds[(size_t)p*DIM + lane];
  float d4 = egu*Eds[(size_t)ng*DIM + lane];
  #pragma unroll
  for (int o = 32; o > 0; o >>= 1) {
    d1 += __shfl_xor(d1, o);
    d2 += __shfl_xor(d2, o);
    d3 += __shfl_xor(d3, o);
    d4 += __shfl_xor(d4, o);
  }
  if (lane == 0) {
    float pterm = fminf(fmaxf(d1*INVT, -5.f), 5.f) + fminf(fmaxf(d2*INVT, -5.f), 5.f);
    float diff = d3 - d4;
    float lr = log1pf(expf(-diff));
    float lg = logf(seg[b] + 1e-8f) + logf(sed[b] + 1e-8f);
    atomicAdd(&accs[0], pterm);
    atomicAdd(&accs[1], lr);
    atomicAdd(&accs[2], lg);
  }
}

__global__ void final_kernel(const float* __restrict__ accs, float* __restrict__ out) {
  float posm = accs[0]*(1.f/BSZ);
  float lr   = accs[1]*(1.f/BSZ);
  float negm = accs[2]*(1.f/BSZ);
  float reg  = 1e-7f*accs[3];
  float l1ls = 0.2f*(negm - posm);
  out[0] = lr + l1ls + reg;
  out[1] = lr;
  out[2] = l1ls;
}

extern "C" void kernel_launch(void* const* d_in, const int* in_sizes, int n_in,
                              void* d_out, int out_size, void* d_ws, size_t ws_size,
                              hipStream_t stream) {
  (void)in_sizes; (void)n_in; (void)out_size;
  const int*   uids = (const int*)d_in[0];
  const int*   iids = (const int*)d_in[1];
  const int*   pos  = (const int*)d_in[2];
  const int*   neg  = (const int*)d_in[3];
  const float* Eg0  = (const float*)d_in[4];
  const float* Ed0  = (const float*)d_in[5];
  const int*   rows = (const int*)d_in[6];
  const int*   cols = (const int*)d_in[7];
  const float* vals = (const float*)d_in[8];
  const float* gms  = (const float*)d_in[9];
  const float* vms  = (const float*)d_in[10];
  const float* ut   = (const float*)d_in[11];
  const float* vt   = (const float*)d_in[12];
  const float* drop = (const float*)d_in[13];
  float* out = (float*)d_out;

  float* ws = (float*)d_ws;
  const size_t ED = (size_t)N_Gc*DIM;  // 3.2M floats
  float* Zg0 = ws;
  float* Zd0 = Zg0 + ED;
  float* Egs = Zd0 + ED;
  float* Eds = Egs + ED;
  // staging overlays the (dead until SpMM) Z/E buffers: NNZ*16B each = 2*ED floats
  int4* stage_r = (int4*)Zg0;
  int4* stage_c = (int4*)Egs;
  int* ptr_r = (int*)(Eds + ED);
  int* ptr_c = ptr_r + (N_Gc + 1);
  int* cur_r = ptr_c + (N_Dc + 1);
  int* cur_c = cur_r + (N_Gc + 1);
  int* bcur_r = cur_c + (N_Dc + 1);
  int* bcur_c = bcur_r + (NBK + 1);
  int*   fcol_r = bcur_c + (NBK + 1);
  float* fw_r0  = (float*)(fcol_r + NNZc);
  float* fw_r1  = fw_r0 + NNZc;
  int*   fcol_c = (int*)(fw_r1 + NNZc);
  float* fw_c0  = (float*)(fcol_c + NNZc);
  float* fw_c1  = fw_c0 + NNZc;
  float* Ggu = fw_c1 + NNZc;
  float* Gdi = Ggu + (size_t)BSZ*DIM;
  float* Mg  = Gdi + (size_t)BSZ*DIM;   // zeroed zone starts here
  float* Md  = Mg + RNK*DIM;
  float* seg = Md + RNK*DIM;
  float* sed = seg + BSZ;
  float* accs = sed + BSZ;              // 16 floats

  size_t need = ((char*)(accs + 16)) - ((char*)d_ws);
  if (ws_size < need) return;

  hipMemsetAsync(cur_r, 0, sizeof(int)*((N_Gc+1) + (N_Dc+1)), stream);
  hipMemsetAsync(Mg, 0, sizeof(float)*(2*RNK*DIM + 2*BSZ + 16), stream);

  hist_kernel<<<(NNZc + 255)/256, 256, 0, stream>>>(rows, cols, cur_r, cur_c);
  scan2_kernel<<<2, 1024, 0, stream>>>(cur_r, ptr_r, cur_c, ptr_c, N_Gc);
  initb_kernel<<<(NBK + 256)/256, 256, 0, stream>>>(ptr_r, ptr_c, bcur_r, bcur_c);
  phaseA_kernel<<<(NNZc + 255)/256, 256, 0, stream>>>(rows, cols, vals, drop, bcur_r, bcur_c, stage_r, stage_c);
  phaseB_kernel<<<NBK, 256, 0, stream>>>(ptr_r, stage_r, fcol_r, fw_r0, fw_r1, N_Gc);
  phaseB_kernel<<<NBK, 256, 0, stream>>>(ptr_c, stage_c, fcol_c, fw_c0, fw_c1, N_Dc);

  int spmm_blocks = (N_Gc + 3)/4;
  // layer 0: Zg0 = A0 @ Ed0 ; Zd0 = A0^T @ Eg0   (overwrites staging — staging already consumed)
  spmm2_kernel<<<spmm_blocks, 256, 0, stream>>>(ptr_r, fcol_r, fw_r0, Ed0, Zg0, nullptr, nullptr, N_Gc);
  spmm2_kernel<<<spmm_blocks, 256, 0, stream>>>(ptr_c, fcol_c, fw_c0, Eg0, Zd0, nullptr, nullptr, N_Dc);
  // layer 1 fused with sum: Egs = Eg0 + Zg0 + A1 @ Zd0 ; Eds = Ed0 + Zd0 + A1^T @ Zg0
  spmm2_kernel<<<spmm_blocks, 256, 0, stream>>>(ptr_r, fcol_r, fw_r1, Zd0, Egs, Eg0, Zg0, N_Gc);
  spmm2_kernel<<<spmm_blocks, 256, 0, stream>>>(ptr_c, fcol_c, fw_c1, Zg0, Eds, Ed0, Zd0, N_Dc);

  // Mg = vt @ (Ed0 + Zd0) ; Md = ut @ (Eg0 + Zg0)
  matred_kernel<<<64, 256, 0, stream>>>(vt, Ed0, Zd0, Mg, N_Dc);
  matred_kernel<<<64, 256, 0, stream>>>(ut, Eg0, Zg0, Md, N_Gc);

  gsmall_kernel<<<BSZ/4, 256, 0, stream>>>(uids, Eg0, gms, Mg, Ggu);
  gsmall_kernel<<<BSZ/4, 256, 0, stream>>>(iids, Ed0, vms, Md, Gdi);

  lse_kernel<<<32*JSEG, 256, 0, stream>>>(Ggu, Egs, N_Gc, seg);
  lse_kernel<<<32*JSEG, 256, 0, stream>>>(Gdi, Eds, N_Dc, sed);

  int n4 = (int)(ED/4);
  sumsq_kernel<<<1024, 256, 0, stream>>>(Eg0, n4, accs + 3);
  sumsq_kernel<<<1024, 256, 0, stream>>>(Ed0, n4, accs + 3);

  perb_kernel<<<BSZ/4, 256, 0, stream>>>(uids, iids, pos, neg, Ggu, Gdi, Egs, Eds, seg, sed, accs);
  final_kernel<<<1, 1, 0, stream>>>(accs, out);
}

// Round 3
// 1229.759 us; speedup vs baseline: 1.5030x; 1.4080x over previous
//
#include <hip/hip_runtime.h>
#include <hip/hip_bf16.h>
#include <math.h>

#define N_Gc 50000
#define N_Dc 50000
#define DIM 64
#define RNK 32
#define NNZc 1600000
#define BSZ 2048
#define KEEPV (1.0f/0.9f)
#define INVT 5.0f
#define NBK 782   // (50000+63)/64 buckets of 64 rows
#define CPAD 16   // ints per bucket cursor (one 64B line each)
#define NSL 24    // j-slices for lse grid

typedef __attribute__((ext_vector_type(8))) short bfrag;
typedef __attribute__((ext_vector_type(4))) float f32x4;

__device__ inline ushort f2bf(float f) {
  union { float f; unsigned int u; } v; v.f = f;
  unsigned int r = (v.u + 0x7fffu + ((v.u >> 16) & 1u)) >> 16;
  return (ushort)r;
}

// ---------------- per-row/col histogram ----------------
__global__ void hist_kernel(const int* __restrict__ rows, const int* __restrict__ cols,
                            int* __restrict__ cur_r, int* __restrict__ cur_c) {
  int e = blockIdx.x*256 + threadIdx.x;
  if (e < NNZc) {
    atomicAdd(&cur_r[rows[e]], 1);
    atomicAdd(&cur_c[cols[e]], 1);
  }
}

__global__ __launch_bounds__(1024) void scan2_kernel(int* curA, int* ptrA, int* curB, int* ptrB, int n) {
  int* cur = blockIdx.x ? curB : curA;
  int* ptr = blockIdx.x ? ptrB : ptrA;
  __shared__ int wsum[16];
  int t = threadIdx.x, lane = t & 63, w = t >> 6;
  int carry = 0;
  for (int base = 0; base < n; base += 1024) {
    int i = base + t;
    int v = (i < n) ? cur[i] : 0;
    int x = v;
    #pragma unroll
    for (int o = 1; o < 64; o <<= 1) { int y = __shfl_up(x, o); if (lane >= o) x += y; }
    if (lane == 63) wsum[w] = x;
    __syncthreads();
    if (t < 16) {
      int s = wsum[t];
      #pragma unroll
      for (int o = 1; o < 16; o <<= 1) { int y = __shfl_up(s, o); if (t >= o) s += y; }
      wsum[t] = s;
    }
    __syncthreads();
    int wpre = (w == 0) ? 0 : wsum[w-1];
    int total = wsum[15];
    int ex = carry + wpre + (x - v);
    if (i < n) ptr[i] = ex;
    carry += total;
    __syncthreads();
  }
  if (t == 0) ptr[n] = carry;
}

// bucket cursors (padded: one per 64B line) start at ptr[first row of bucket]
__global__ void initb_kernel(const int* __restrict__ ptr_r, const int* __restrict__ ptr_c,
                             int* __restrict__ bcur_r, int* __restrict__ bcur_c) {
  int b = blockIdx.x*256 + threadIdx.x;
  if (b <= NBK) {
    int r = min(b*64, N_Gc);
    bcur_r[b*CPAD] = ptr_r[r];
    bcur_c[b*CPAD] = ptr_c[r];
  }
}

// ---------------- phase A: scatter packed records into bucket regions ----------------
__global__ __launch_bounds__(256) void phaseA_kernel(const int* __restrict__ rows, const int* __restrict__ cols,
    const float* __restrict__ vals, const float* __restrict__ drop,
    int* __restrict__ bcur_r, int* __restrict__ bcur_c,
    int4* __restrict__ stage_r, int4* __restrict__ stage_c) {
  int e = blockIdx.x*256 + threadIdx.x;
  if (e >= NNZc) return;
  int r = rows[e], c = cols[e];
  float v = vals[e];
  float wr0 = v*((drop[e] > 0.1f) ? KEEPV : 0.f);
  float wc0 = v*((drop[(size_t)NNZc + e] > 0.1f) ? KEEPV : 0.f);
  float wr1 = v*((drop[2*(size_t)NNZc + e] > 0.1f) ? KEEPV : 0.f);
  float wc1 = v*((drop[3*(size_t)NNZc + e] > 0.1f) ? KEEPV : 0.f);
  int p = atomicAdd(&bcur_r[(r >> 6)*CPAD], 1);
  stage_r[p] = make_int4(c, __float_as_int(wr0), __float_as_int(wr1), r);
  int q = atomicAdd(&bcur_c[(c >> 6)*CPAD], 1);
  stage_c[q] = make_int4(r, __float_as_int(wc0), __float_as_int(wc1), c);
}

// ---------------- phase B: within-bucket counting sort to exact CSR slots ----------------
__global__ __launch_bounds__(256) void phaseB_kernel(const int* __restrict__ ptr,
    const int4* __restrict__ stage, int* __restrict__ fcol,
    float* __restrict__ fw0, float* __restrict__ fw1, int n) {
  __shared__ int cnt[64];
  int t = threadIdx.x;
  int base_row = blockIdx.x*64;
  int lastrow = min(base_row + 64, n);
  int base = ptr[base_row];
  int endp = ptr[lastrow];
  if (t < 64) {
    int rr = base_row + t;
    cnt[t] = (rr < n) ? (ptr[rr] - base) : 0;
  }
  __syncthreads();
  for (int k = base + t; k < endp; k += 256) {
    int4 rec = stage[k];
    int rel = rec.w - base_row;
    int pos = base + atomicAdd(&cnt[rel], 1);
    fcol[pos] = rec.x;
    fw0[pos] = __int_as_float(rec.y);
    fw1[pos] = __int_as_float(rec.z);
  }
}

// ---------------- SpMM: wave per row, lane = dim, sequential records ----------------
__global__ __launch_bounds__(256) void spmm2_kernel(const int* __restrict__ ptr,
    const int* __restrict__ fcol, const float* __restrict__ fw,
    const float* __restrict__ Esrc, float* __restrict__ Zdst,
    const float* __restrict__ addA, const float* __restrict__ addB, int nrows) {
  int lane = threadIdx.x & 63;
  int row = blockIdx.x*4 + (threadIdx.x >> 6);
  if (row >= nrows) return;
  int k = ptr[row], end = ptr[row+1];
  float acc = 0.f;
  for (; k + 4 <= end; k += 4) {
    int c0 = fcol[k], c1 = fcol[k+1], c2 = fcol[k+2], c3 = fcol[k+3];
    float w0 = fw[k], w1 = fw[k+1], w2 = fw[k+2], w3 = fw[k+3];
    float g0 = Esrc[(size_t)c0*DIM + lane];
    float g1 = Esrc[(size_t)c1*DIM + lane];
    float g2 = Esrc[(size_t)c2*DIM + lane];
    float g3 = Esrc[(size_t)c3*DIM + lane];
    acc += w0*g0; acc += w1*g1; acc += w2*g2; acc += w3*g3;
  }
  for (; k < end; k++)
    acc += fw[k]*Esrc[(size_t)fcol[k]*DIM + lane];
  size_t o = (size_t)row*DIM + lane;
  if (addA != nullptr) acc += addA[o] + addB[o];
  Zdst[o] = acc;
}

// ---------------- M[32][64] = vrow @ (E0 + Z0) ----------------
__global__ __launch_bounds__(256) void matred_kernel(const float* __restrict__ vrow,
    const float* __restrict__ E0, const float* __restrict__ Z0, float* __restrict__ M, int n) {
  __shared__ float part[RNK*DIM];
  int t = threadIdx.x, lane = t & 63, w = t >> 6;
  for (int i = t; i < RNK*DIM; i += 256) part[i] = 0.f;
  __syncthreads();
  int nw = gridDim.x*4;
  int wid = blockIdx.x*4 + w;
  int chunk = (n + nw - 1)/nw;
  int i0 = wid*chunk, i1 = min(n, i0 + chunk);
  float acc[RNK];
  #pragma unroll
  for (int r = 0; r < RNK; r++) acc[r] = 0.f;
  for (int i = i0; i < i1; i++) {
    float x = E0[(size_t)i*DIM + lane] + Z0[(size_t)i*DIM + lane];
    #pragma unroll
    for (int r = 0; r < RNK; r++) acc[r] += vrow[(size_t)r*n + i]*x;
  }
  #pragma unroll
  for (int r = 0; r < RNK; r++) atomicAdd(&part[r*DIM + lane], acc[r]);
  __syncthreads();
  for (int i = t; i < RNK*DIM; i += 256) atomicAdd(&M[i], part[i]);
}

// ---------------- G rows at sampled ids ----------------
__global__ __launch_bounds__(256) void gsmall_kernel(const int* __restrict__ ids,
    const float* __restrict__ E0, const float* __restrict__ mul, const float* __restrict__ M,
    float* __restrict__ out) {
  __shared__ float Ms[RNK*DIM];
  int t = threadIdx.x;
  for (int i = t; i < RNK*DIM; i += 256) Ms[i] = M[i];
  __syncthreads();
  int b = blockIdx.x*4 + (t >> 6), lane = t & 63;
  int u = ids[b];
  float a = E0[(size_t)u*DIM + lane];
  #pragma unroll
  for (int r = 0; r < RNK; r++) a += mul[(size_t)u*RNK + r]*Ms[r*DIM + lane];
  out[(size_t)b*DIM + lane] = a;
}

// ---------------- fp32 -> bf16 (RNE) conversion ----------------
__global__ __launch_bounds__(256) void conv_kernel(const float4* __restrict__ in,
    ushort4* __restrict__ out, int n4) {
  int i = blockIdx.x*256 + threadIdx.x;
  if (i < n4) {
    float4 v = in[i];
    ushort4 o;
    o.x = f2bf(v.x); o.y = f2bf(v.y); o.z = f2bf(v.z); o.w = f2bf(v.w);
    out[i] = o;
  }
}

// ---------------- bf16 MFMA fused GEMM + exp + row-sum ----------------
// sumexp[b] += sum_j exp( dot(A[b],X[j]) * INVT ), A: 2048x64 bf16, X: nj x 64 bf16
__global__ __launch_bounds__(256) void lse_mfma_kernel(const ushort* __restrict__ A,
    const ushort* __restrict__ X, int nj, float* __restrict__ sumexp) {
  __shared__ __align__(16) ushort Xs[64*68];   // padded stride 68 (136B rows)
  int t = threadIdx.x, lane = t & 63, w = t >> 6;
  int bt = blockIdx.x & 31, js = blockIdx.x >> 5;
  int b0 = bt*64;
  int m = lane & 15, q = lane >> 4;
  // A-fragments straight from global (held in regs for whole kernel)
  // A layout (M=16 x K=32): row = lane&15, k = (lane>>4)*8 + i (contiguous 8)
  const ushort* Arow = A + (size_t)(b0 + w*16 + m)*DIM + q*8;
  bfrag a0 = *(const bfrag*)(Arow);        // k in [0,32)
  bfrag a1 = *(const bfrag*)(Arow + 32);   // k in [32,64)
  float rs0 = 0.f, rs1 = 0.f, rs2 = 0.f, rs3 = 0.f;
  int njt = (nj + 63) >> 6;
  for (int jt = js; jt < njt; jt += NSL) {
    int j0 = jt << 6;
    __syncthreads();
    // stage 64 X-rows (128B each) into padded LDS
    for (int c = t; c < 512; c += 256) {
      int r = c >> 3, k8 = (c & 7) << 3;
      int j = j0 + r;
      ushort4 v0 = {0,0,0,0}, v1 = {0,0,0,0};
      if (j < nj) {
        const ushort4* src = (const ushort4*)(X + (size_t)j*DIM + k8);
        v0 = src[0]; v1 = src[1];
      }
      *(ushort4*)&Xs[r*68 + k8]     = v0;
      *(ushort4*)&Xs[r*68 + k8 + 4] = v1;
    }
    __syncthreads();
    #pragma unroll
    for (int jq = 0; jq < 4; jq++) {
      int jr = jq*16 + m;
      // B layout mirrors A: col = lane&15 (the j row of X), k = (lane>>4)*8 + i
      union { bfrag f; uint2 u2[2]; } B0, B1;
      B0.u2[0] = *(const uint2*)&Xs[jr*68 + q*8];
      B0.u2[1] = *(const uint2*)&Xs[jr*68 + q*8 + 4];
      B1.u2[0] = *(const uint2*)&Xs[jr*68 + 32 + q*8];
      B1.u2[1] = *(const uint2*)&Xs[jr*68 + 32 + q*8 + 4];
      f32x4 acc = {0.f, 0.f, 0.f, 0.f};
      acc = __builtin_amdgcn_mfma_f32_16x16x32_bf16(a0, B0.f, acc, 0, 0, 0);
      acc = __builtin_amdgcn_mfma_f32_16x16x32_bf16(a1, B1.f, acc, 0, 0, 0);
      // C/D: col = lane&15 (j), row = (lane>>4)*4 + reg (b)
      int jg = j0 + jr;
      if (jg < nj) {
        rs0 += __expf(acc[0]*INVT);
        rs1 += __expf(acc[1]*INVT);
        rs2 += __expf(acc[2]*INVT);
        rs3 += __expf(acc[3]*INVT);
      }
    }
  }
  #pragma unroll
  for (int o = 1; o < 16; o <<= 1) {
    rs0 += __shfl_xor(rs0, o);
    rs1 += __shfl_xor(rs1, o);
    rs2 += __shfl_xor(rs2, o);
    rs3 += __shfl_xor(rs3, o);
  }
  if (m == 0) {
    float* dst = &sumexp[b0 + w*16 + q*4];
    atomicAdd(&dst[0], rs0);
    atomicAdd(&dst[1], rs1);
    atomicAdd(&dst[2], rs2);
    atomicAdd(&dst[3], rs3);
  }
}

// ---------------- sum of squares ----------------
__global__ __launch_bounds__(256) void sumsq_kernel(const float* __restrict__ x, int n4, float* __restrict__ acc) {
  int idx = blockIdx.x*256 + threadIdx.x;
  int stride = gridDim.x*256;
  float s = 0.f;
  for (int i = idx; i < n4; i += stride) {
    float4 v = ((const float4*)x)[i];
    s += v.x*v.x + v.y*v.y + v.z*v.z + v.w*v.w;
  }
  #pragma unroll
  for (int o = 32; o > 0; o >>= 1) s += __shfl_xor(s, o);
  if ((threadIdx.x & 63) == 0) atomicAdd(acc, s);
}

// ---------------- per-sample terms ----------------
__global__ __launch_bounds__(256) void perb_kernel(const int* __restrict__ uids, const int* __restrict__ iids,
    const int* __restrict__ pos, const int* __restrict__ neg,
    const float* __restrict__ Ggu, const float* __restrict__ Gdi,
    const float* __restrict__ Egs, const float* __restrict__ Eds,
    const float* __restrict__ seg, const float* __restrict__ sed,
    float* __restrict__ accs) {
  int t = threadIdx.x, lane = t & 63;
  int b = blockIdx.x*4 + (t >> 6);
  int u = uids[b], it = iids[b], p = pos[b], ng = neg[b];
  float egu = Egs[(size_t)u*DIM + lane];
  float d1 = Ggu[(size_t)b*DIM + lane]*egu;
  float d2 = Gdi[(size_t)b*DIM + lane]*Eds[(size_t)it*DIM + lane];
  float d3 = egu*Eds[(size_t)p*DIM + lane];
  float d4 = egu*Eds[(size_t)ng*DIM + lane];
  #pragma unroll
  for (int o = 32; o > 0; o >>= 1) {
    d1 += __shfl_xor(d1, o);
    d2 += __shfl_xor(d2, o);
    d3 += __shfl_xor(d3, o);
    d4 += __shfl_xor(d4, o);
  }
  if (lane == 0) {
    float pterm = fminf(fmaxf(d1*INVT, -5.f), 5.f) + fminf(fmaxf(d2*INVT, -5.f), 5.f);
    float diff = d3 - d4;
    float lr = log1pf(expf(-diff));
    float lg = logf(seg[b] + 1e-8f) + logf(sed[b] + 1e-8f);
    atomicAdd(&accs[0], pterm);
    atomicAdd(&accs[1], lr);
    atomicAdd(&accs[2], lg);
  }
}

__global__ void final_kernel(const float* __restrict__ accs, float* __restrict__ out) {
  float posm = accs[0]*(1.f/BSZ);
  float lr   = accs[1]*(1.f/BSZ);
  float negm = accs[2]*(1.f/BSZ);
  float reg  = 1e-7f*accs[3];
  float l1ls = 0.2f*(negm - posm);
  out[0] = lr + l1ls + reg;
  out[1] = lr;
  out[2] = l1ls;
}

extern "C" void kernel_launch(void* const* d_in, const int* in_sizes, int n_in,
                              void* d_out, int out_size, void* d_ws, size_t ws_size,
                              hipStream_t stream) {
  (void)in_sizes; (void)n_in; (void)out_size;
  const int*   uids = (const int*)d_in[0];
  const int*   iids = (const int*)d_in[1];
  const int*   pos  = (const int*)d_in[2];
  const int*   neg  = (const int*)d_in[3];
  const float* Eg0  = (const float*)d_in[4];
  const float* Ed0  = (const float*)d_in[5];
  const int*   rows = (const int*)d_in[6];
  const int*   cols = (const int*)d_in[7];
  const float* vals = (const float*)d_in[8];
  const float* gms  = (const float*)d_in[9];
  const float* vms  = (const float*)d_in[10];
  const float* ut   = (const float*)d_in[11];
  const float* vt   = (const float*)d_in[12];
  const float* drop = (const float*)d_in[13];
  float* out = (float*)d_out;

  float* ws = (float*)d_ws;
  const size_t ED = (size_t)N_Gc*DIM;  // 3.2M floats
  float* Zg0 = ws;
  float* Zd0 = Zg0 + ED;
  float* Egs = Zd0 + ED;
  float* Eds = Egs + ED;
  // staging overlays the (dead until SpMM) Z/E buffers: NNZ*16B each = 2*ED floats
  int4* stage_r = (int4*)Zg0;
  int4* stage_c = (int4*)Egs;
  int* ptr_r = (int*)(Eds + ED);
  int* ptr_c = ptr_r + (N_Gc + 1);
  int* cur_r = ptr_c + (N_Dc + 1);
  int* cur_c = cur_r + (N_Gc + 1);
  int* bcur_r = cur_c + (N_Dc + 1);
  int* bcur_c = bcur_r + (NBK + 1)*CPAD;
  int*   fcol_r = bcur_c + (NBK + 1)*CPAD;
  float* fw_r0  = (float*)(fcol_r + NNZc);
  float* fw_r1  = fw_r0 + NNZc;
  int*   fcol_c = (int*)(fw_r1 + NNZc);
  float* fw_c0  = (float*)(fcol_c + NNZc);
  float* fw_c1  = fw_c0 + NNZc;
  float* Ggu = fw_c1 + NNZc;
  float* Gdi = Ggu + (size_t)BSZ*DIM;
  float* Mg  = Gdi + (size_t)BSZ*DIM;   // zeroed zone starts here
  float* Md  = Mg + RNK*DIM;
  float* seg = Md + RNK*DIM;
  float* sed = seg + BSZ;
  float* accs = sed + BSZ;              // 16 floats
  // bf16 views overlaying r-side fcol/fw arrays (dead after 3rd spmm2)
  ushort* Egs_b = (ushort*)fcol_r;              // 6.4MB needed, 6.4MB avail
  ushort* Eds_b = (ushort*)fw_r0;
  ushort* Ggu_b = (ushort*)fw_r1;               // 256KB
  ushort* Gdi_b = Ggu_b + (size_t)BSZ*DIM;      // next 256KB (still within fw_r1)

  size_t need = ((char*)(accs + 16)) - ((char*)d_ws);
  if (ws_size < need) return;

  hipMemsetAsync(cur_r, 0, sizeof(int)*((N_Gc+1) + (N_Dc+1)), stream);
  hipMemsetAsync(Mg, 0, sizeof(float)*(2*RNK*DIM + 2*BSZ + 16), stream);

  hist_kernel<<<(NNZc + 255)/256, 256, 0, stream>>>(rows, cols, cur_r, cur_c);
  scan2_kernel<<<2, 1024, 0, stream>>>(cur_r, ptr_r, cur_c, ptr_c, N_Gc);
  initb_kernel<<<(NBK + 256)/256, 256, 0, stream>>>(ptr_r, ptr_c, bcur_r, bcur_c);
  phaseA_kernel<<<(NNZc + 255)/256, 256, 0, stream>>>(rows, cols, vals, drop, bcur_r, bcur_c, stage_r, stage_c);
  phaseB_kernel<<<NBK, 256, 0, stream>>>(ptr_r, stage_r, fcol_r, fw_r0, fw_r1, N_Gc);
  phaseB_kernel<<<NBK, 256, 0, stream>>>(ptr_c, stage_c, fcol_c, fw_c0, fw_c1, N_Dc);

  int spmm_blocks = (N_Gc + 3)/4;
  // layer 0: Zg0 = A0 @ Ed0 ; Zd0 = A0^T @ Eg0   (overwrites staging — already consumed)
  spmm2_kernel<<<spmm_blocks, 256, 0, stream>>>(ptr_r, fcol_r, fw_r0, Ed0, Zg0, nullptr, nullptr, N_Gc);
  spmm2_kernel<<<spmm_blocks, 256, 0, stream>>>(ptr_c, fcol_c, fw_c0, Eg0, Zd0, nullptr, nullptr, N_Dc);
  // layer 1 fused with sum: Egs = Eg0 + Zg0 + A1 @ Zd0 ; Eds = Ed0 + Zd0 + A1^T @ Zg0
  spmm2_kernel<<<spmm_blocks, 256, 0, stream>>>(ptr_r, fcol_r, fw_r1, Zd0, Egs, Eg0, Zg0, N_Gc);
  spmm2_kernel<<<spmm_blocks, 256, 0, stream>>>(ptr_c, fcol_c, fw_c1, Zg0, Eds, Ed0, Zd0, N_Dc);

  // Mg = vt @ (Ed0 + Zd0) ; Md = ut @ (Eg0 + Zg0)
  matred_kernel<<<64, 256, 0, stream>>>(vt, Ed0, Zd0, Mg, N_Dc);
  matred_kernel<<<64, 256, 0, stream>>>(ut, Eg0, Zg0, Md, N_Gc);

  gsmall_kernel<<<BSZ/4, 256, 0, stream>>>(uids, Eg0, gms, Mg, Ggu);
  gsmall_kernel<<<BSZ/4, 256, 0, stream>>>(iids, Ed0, vms, Md, Gdi);

  // fp32 -> bf16 (into dead r-side CSR arrays)
  int n4 = (int)(ED/4);
  conv_kernel<<<(n4 + 255)/256, 256, 0, stream>>>((const float4*)Egs, (ushort4*)Egs_b, n4);
  conv_kernel<<<(n4 + 255)/256, 256, 0, stream>>>((const float4*)Eds, (ushort4*)Eds_b, n4);
  int g4 = BSZ*DIM/4;
  conv_kernel<<<(g4 + 255)/256, 256, 0, stream>>>((const float4*)Ggu, (ushort4*)Ggu_b, g4);
  conv_kernel<<<(g4 + 255)/256, 256, 0, stream>>>((const float4*)Gdi, (ushort4*)Gdi_b, g4);

  lse_mfma_kernel<<<32*NSL, 256, 0, stream>>>(Ggu_b, Egs_b, N_Gc, seg);
  lse_mfma_kernel<<<32*NSL, 256, 0, stream>>>(Gdi_b, Eds_b, N_Dc, sed);

  sumsq_kernel<<<1024, 256, 0, stream>>>(Eg0, n4, accs + 3);
  sumsq_kernel<<<1024, 256, 0, stream>>>(Ed0, n4, accs + 3);

  perb_kernel<<<BSZ/4, 256, 0, stream>>>(uids, iids, pos, neg, Ggu, Gdi, Egs, Eds, seg, sed, accs);
  final_kernel<<<1, 1, 0, stream>>>(accs, out);
}